// Round 4
// baseline (295.636 us; speedup 1.0000x reference)
//
#include <hip/hip_runtime.h>

// VQ-VAE nearest-codebook quantization via bf16 MFMA.
// x: [64,256,32,32] fp32, emb: [512,256] fp32.
// out0 = codes NCHW, out1 = x, out2 = codes NCHW.
// dist argmin: s_k = ||e_k||^2 - 2 z.e_k  (||z||^2 dropped, constant per pos).
// bf16 rounding can flip near-ties; flip error <= 2/512 = 3.9e-3 (emb entries
// are bounded by 1/512, so ANY selection flip changes output by <= 2/512).
//
// R5: after R4's TA-divergence fix (-45us), remaining slack = scatter's x
// re-read (67MB), 1:1 ds_read:MFMA ratio in the chunk loop, and idx round
// trip. Changes: (1) out1 written from argmin's staged LDS x-tile (coalesced
// 256B row stores) -> scatter drops its x read; (2) block = 128 positions,
// each wave owns 2 MFMA pos-tiles -> 16 b128 reads feed 32 MFMAs per chunk,
// codebook L2 traffic halved (134MB total); (3) scatter-lite writes only
// out0/out2. Every VMEM instr stays <=2 contiguous segments (R1-R4 lesson).

#define B_  64
#define D_  256
#define HW_ 1024
#define K_  512

typedef __attribute__((ext_vector_type(8))) short short8;
typedef __attribute__((ext_vector_type(4))) float f32x4;

__device__ unsigned short g_ebf[K_ * D_];  // emb in bf16, row-major [k][d]
__device__ float g_e2[K_];                 // ||e_k||^2 fp32
__device__ float g_embT[D_ * K_];          // emb^T fp32 [d][k] for scatter gathers
__device__ int   g_idx[B_ * HW_];          // argmin indices

__device__ __forceinline__ unsigned short f2bf(float f) {
    unsigned u = __float_as_uint(f);
    u += 0x7fffu + ((u >> 16) & 1u);       // round-to-nearest-even
    return (unsigned short)(u >> 16);
}

// prep: emb fp32 -> bf16 + row norms + fp32 transpose. 64 blocks x 256 thr.
__global__ void prep(const float* __restrict__ emb) {
    const int t   = threadIdx.x;
    const int row = blockIdx.x * 8 + (t >> 5);
    const int c0  = (t & 31) * 8;
    const float* rp = emb + row * D_ + c0;
    float4 a = *(const float4*)rp;
    float4 b = *(const float4*)(rp + 4);
    short8 v;
    v[0] = (short)f2bf(a.x); v[1] = (short)f2bf(a.y);
    v[2] = (short)f2bf(a.z); v[3] = (short)f2bf(a.w);
    v[4] = (short)f2bf(b.x); v[5] = (short)f2bf(b.y);
    v[6] = (short)f2bf(b.z); v[7] = (short)f2bf(b.w);
    *(short8*)(g_ebf + row * D_ + c0) = v;
    g_embT[(c0 + 0) * K_ + row] = a.x;
    g_embT[(c0 + 1) * K_ + row] = a.y;
    g_embT[(c0 + 2) * K_ + row] = a.z;
    g_embT[(c0 + 3) * K_ + row] = a.w;
    g_embT[(c0 + 4) * K_ + row] = b.x;
    g_embT[(c0 + 5) * K_ + row] = b.y;
    g_embT[(c0 + 6) * K_ + row] = b.z;
    g_embT[(c0 + 7) * K_ + row] = b.w;
    float ps = a.x*a.x + a.y*a.y + a.z*a.z + a.w*a.w
             + b.x*b.x + b.y*b.y + b.z*b.z + b.w*b.w;
    ps += __shfl_xor(ps, 1);  ps += __shfl_xor(ps, 2);
    ps += __shfl_xor(ps, 4);  ps += __shfl_xor(ps, 8);
    ps += __shfl_xor(ps, 16);
    if ((t & 31) == 0) g_e2[row] = ps;
}

// argmin+out1: 512 blocks x 256 thr (4 waves). Block = (b, 128 positions).
// Wave w owns 32 positions (2 ptiles of 16) vs ALL 512 codes.
// Phase A (4 rounds): stage [64d][128pos] f32 (32KB, aliased on cb) via
// global_load_lds; build B-frags; write out1 rows (256B coalesced stores).
// Phase B: 16 chunks x 32 codes, LDS dbuf, pre-swizzled staging + swizzled
// ds_read_b128 A-frags (conflict-free), 2 accumulators per chunk-subtile.
__global__ __launch_bounds__(256, 4)
void vq_argmin(const float* __restrict__ x, float* __restrict__ out1) {
    __shared__ unsigned short cb[2][32 * 256];   // 2 x 16KB chunk buffers (32KB)

    const int t   = threadIdx.x;
    const int w   = t >> 6;
    const int l   = t & 63;
    const int blk = blockIdx.x;
    const int b   = blk >> 3;
    const int hw0 = (blk & 7) << 7;
    const float* xb = x    + ((size_t)b * D_) * HW_ + hw0;
    float*       o1 = out1 + ((size_t)b * D_) * HW_ + hw0;

    // ---- phase A: build zb (B-frags, 2 ptiles) + out1 copy ----
    short8 zb[2][8];
    float* xt = (float*)&cb[0][0];               // [64][128] f32 tile, 32KB
    for (int R = 0; R < 4; ++R) {
#pragma unroll
        for (int k2 = 0; k2 < 8; ++k2) {
            const int k  = 8 * w + k2;           // instr 0..31, 1KB each
            const int dr = 2 * k + (l >> 5);     // local d-row 0..63
            const float* gp = xb + (size_t)(64 * R + dr) * HW_ + (l & 31) * 4;
            float* lp = xt + 256 * k;            // wave-uniform base; HW adds lane*16B
            __builtin_amdgcn_global_load_lds(
                (const __attribute__((address_space(1))) unsigned int*)gp,
                (__attribute__((address_space(3))) unsigned int*)lp, 16, 0, 0);
        }
        __syncthreads();                         // drains vmcnt
#pragma unroll
        for (int h = 0; h < 2; ++h) {
#pragma unroll
            for (int pt = 0; pt < 2; ++pt) {
                short8 f;
#pragma unroll
                for (int j = 0; j < 8; ++j) {
                    const int dl = 32 * h + (l >> 4) * 8 + j;
                    f[j] = (short)f2bf(xt[dl * 128 + 32 * w + 16 * pt + (l & 15)]);
                }
                zb[pt][2 * R + h] = f;
            }
        }
        // out1 copy: wave w writes local d-rows [16w, 16w+16), 2 half-rows each
#pragma unroll
        for (int rr = 0; rr < 16; ++rr) {
            const int dl = 16 * w + rr;
            const size_t gro = (size_t)(64 * R + dl) * HW_;
#pragma unroll
            for (int h2 = 0; h2 < 2; ++h2) {
                const float vv = xt[dl * 128 + 64 * h2 + l];
                __builtin_nontemporal_store(vv, o1 + gro + 64 * h2 + l);
            }
        }
        __syncthreads();                         // next round overwrites xt
    }

    // ---- phase B: 16 chunks x 32 codes, dbuf, swizzled frag reads ----
#define STAGEC(cc, bb) do {                                                   \
        _Pragma("unroll")                                                     \
        for (int k2 = 0; k2 < 4; ++k2) {                                      \
            const int k  = 4 * w + k2;                                        \
            const int rl = 2 * k + (l >> 5);       /* local code row 0..31 */ \
            const unsigned short* gp = g_ebf + ((cc) * 32 + rl) * 256         \
                                       + (((l & 31) ^ (rl & 7)) << 3);        \
            unsigned short* lp = &cb[bb][512 * k];                            \
            __builtin_amdgcn_global_load_lds(                                 \
                (const __attribute__((address_space(1))) unsigned int*)gp,    \
                (__attribute__((address_space(3))) unsigned int*)lp, 16, 0, 0);\
        }                                                                     \
    } while (0)

    float minv0 = 3.0e38f, minv1 = 3.0e38f;
    int   mini0 = 0,       mini1 = 0;

    STAGEC(0, 0);
    __syncthreads();
    for (int c = 0; c < 16; ++c) {
        if (c + 1 < 16) STAGEC(c + 1, (c + 1) & 1);   // prefetch next chunk
        const unsigned short* cbuf = cb[c & 1];
#pragma unroll
        for (int ct2 = 0; ct2 < 2; ++ct2) {
            f32x4 a0 = {0.f, 0.f, 0.f, 0.f}, a1 = {0.f, 0.f, 0.f, 0.f};
            const int cr = ct2 * 16 + (l & 15);       // local code row
#pragma unroll
            for (int s = 0; s < 8; ++s) {
                const int unit = ((l >> 4) + 4 * s) ^ (cr & 7);  // 16B unit, swizzled
                short8 a = *(const short8*)(cbuf + cr * 256 + unit * 8);
                a0 = __builtin_amdgcn_mfma_f32_16x16x32_bf16(a, zb[0][s], a0, 0, 0, 0);
                a1 = __builtin_amdgcn_mfma_f32_16x16x32_bf16(a, zb[1][s], a1, 0, 0, 0);
            }
            const int cbase = 32 * c + 16 * ct2 + (l >> 4) * 4;
            f32x4 e2v = *(const f32x4*)(g_e2 + cbase);
#pragma unroll
            for (int r = 0; r < 4; ++r) {
                const float s0 = e2v[r] - 2.0f * a0[r];
                const float s1 = e2v[r] - 2.0f * a1[r];
                if (s0 < minv0) { minv0 = s0; mini0 = cbase + r; }
                if (s1 < minv1) { minv1 = s1; mini1 = cbase + r; }
            }
        }
        __syncthreads();   // all waves done reading cbuf; prefetch landed
    }

    // cross-lane argmin merge: lanes {p, p+16, p+32, p+48} share a position
    {
        float ov; int oi;
        ov = __shfl_xor(minv0, 16); oi = __shfl_xor(mini0, 16);
        if (ov < minv0 || (ov == minv0 && oi < mini0)) { minv0 = ov; mini0 = oi; }
        ov = __shfl_xor(minv0, 32); oi = __shfl_xor(mini0, 32);
        if (ov < minv0 || (ov == minv0 && oi < mini0)) { minv0 = ov; mini0 = oi; }
        ov = __shfl_xor(minv1, 16); oi = __shfl_xor(mini1, 16);
        if (ov < minv1 || (ov == minv1 && oi < mini1)) { minv1 = ov; mini1 = oi; }
        ov = __shfl_xor(minv1, 32); oi = __shfl_xor(mini1, 32);
        if (ov < minv1 || (ov == minv1 && oi < mini1)) { minv1 = ov; mini1 = oi; }
    }
    if (l < 16) {
        g_idx[b * HW_ + hw0 + 32 * w + l]      = mini0;
        g_idx[b * HW_ + hw0 + 32 * w + 16 + l] = mini1;
    }
}

// scatter-lite: 2048 blocks x 256 thr. Block = (b, 8 d-rows); thread owns 4
// contiguous hw positions. Writes out0/out2 only (full 4KB-contiguous rows).
// Codes gathered from embT rows staged in LDS (16KB) -> no TA divergence.
__global__ __launch_bounds__(256)
void vq_scatter(float* __restrict__ out0, float* __restrict__ out2) {
    __shared__ float et[8 * 512];
    const int t   = threadIdx.x;
    const int blk = blockIdx.x;
    const int b   = blk >> 5;
    const int d0  = (blk & 31) << 3;
    {
        const float4* src = (const float4*)(g_embT + (size_t)d0 * K_);
        float4* dst = (float4*)et;
#pragma unroll
        for (int i = 0; i < 4; ++i) dst[t + 256 * i] = src[t + 256 * i];
    }
    const int4 mi = *(const int4*)(g_idx + b * HW_ + 4 * t);
    __syncthreads();
    const size_t base = ((size_t)b * D_ + d0) * HW_ + 4 * t;
    float* p0 = out0 + base;
    float* p2 = out2 + base;
#pragma unroll
    for (int r = 0; r < 8; ++r) {
        const float* er = et + r * 512;
        const size_t off = (size_t)r * HW_;
        f32x4 cv;
        cv[0] = er[mi.x]; cv[1] = er[mi.y];
        cv[2] = er[mi.z]; cv[3] = er[mi.w];
        __builtin_nontemporal_store(cv, (f32x4*)(p0 + off));
        __builtin_nontemporal_store(cv, (f32x4*)(p2 + off));
    }
}

extern "C" void kernel_launch(void* const* d_in, const int* in_sizes, int n_in,
                              void* d_out, int out_size, void* d_ws, size_t ws_size,
                              hipStream_t stream) {
    const float* x   = (const float*)d_in[0];
    const float* emb = (const float*)d_in[1];
    float* out0 = (float*)d_out;
    float* out1 = out0 + (size_t)16777216;
    float* out2 = out0 + (size_t)33554432;

    prep<<<64, 256, 0, stream>>>(emb);
    vq_argmin<<<512, 256, 0, stream>>>(x, out1);
    vq_scatter<<<2048, 256, 0, stream>>>(out0, out2);
}